// Round 1
// baseline (298.566 us; speedup 1.0000x reference)
//
#include <hip/hip_runtime.h>
#include <stdint.h>
#include <stddef.h>

typedef _Float16 f16;
typedef __attribute__((ext_vector_type(8))) _Float16 f16x8;
typedef __attribute__((ext_vector_type(4))) float f32x4;

#define GPTR(p) ((const __attribute__((address_space(1))) void*)(p))
#define LPTR(p) ((__attribute__((address_space(3))) void*)(p))

// async global->LDS, 16B per lane; LDS dest = wave-uniform base + lane*16
__device__ __forceinline__ void async16(const void* g, void* l) {
    __builtin_amdgcn_global_load_lds(GPTR(g), LPTR(l), 16, 0, 0);
}

#define VMCNT(N) asm volatile("s_waitcnt vmcnt(" #N ")" ::: "memory")
#define SBAR()   do { __builtin_amdgcn_sched_barrier(0); \
                      __builtin_amdgcn_s_barrier();      \
                      __builtin_amdgcn_sched_barrier(0); } while (0)

// ---------------------------------------------------------------------------
// Sparsify (2:4 soft-threshold along last dim of W[K][M]) * scale -> fp16,
// stored transposed Wt[M][K]. Tiled 64x64 with LDS transpose. (unchanged)
// ---------------------------------------------------------------------------
__global__ __launch_bounds__(256) void sparsify_t_tiled(
        const float* __restrict__ W, const float* __restrict__ scale,
        f16* __restrict__ Wt, int K, int M) {
    __shared__ f16 T[64][80];
    const int r0 = blockIdx.y << 6, m0 = blockIdx.x << 6;
    const float s = scale[0];
    const int t = threadIdx.x;
    const int rr = t >> 2, mb = (t & 3) << 4;
    const float* src = W + (size_t)(r0 + rr) * M + m0 + mb;
    #pragma unroll
    for (int j = 0; j < 4; j++) {
        float4 v = *(const float4*)(src + j * 4);
        float a0 = fabsf(v.x), a1 = fabsf(v.y), a2 = fabsf(v.z), a3 = fabsf(v.w);
        float lo1 = fminf(a0, a1), hi1 = fmaxf(a0, a1);
        float lo2 = fminf(a2, a3), hi2 = fmaxf(a2, a3);
        float th = fminf(fmaxf(lo1, lo2), fminf(hi1, hi2));
        int m = mb + j * 4;
        T[m + 0][rr] = (f16)(copysignf(fmaxf(a0 - th, 0.f), v.x) * s);
        T[m + 1][rr] = (f16)(copysignf(fmaxf(a1 - th, 0.f), v.y) * s);
        T[m + 2][rr] = (f16)(copysignf(fmaxf(a2 - th, 0.f), v.z) * s);
        T[m + 3][rr] = (f16)(copysignf(fmaxf(a3 - th, 0.f), v.w) * s);
    }
    __syncthreads();
    const int mm = t >> 2, rb = (t & 3) << 4;
    f16* dst = Wt + (size_t)(m0 + mm) * K + r0 + rb;
    *(f16x8*)dst       = *(const f16x8*)&T[mm][rb];
    *(f16x8*)(dst + 8) = *(const f16x8*)&T[mm][rb + 8];
}

// ---------------------------------------------------------------------------
// GEMM1: H[16384][256](f16) = fp16(x[16384][2048]) @ W1t[256][2048]^T + b1
// BM=64, BN=256 (full R -> A-panel read exactly once), BK=32.
// 512 threads = 8 waves as 2m x 4n of 32x64 wave-tiles. Grid = 256 blocks.
// Double-buffered LDS (48 KB), counted-vmcnt pipeline: stage(t+1) issued
// before waiting on stage(t); loads stay in flight across raw s_barrier.
// XOR-swizzled staging via pre-swizzled global source (LDS linear).
// ---------------------------------------------------------------------------
__global__ __launch_bounds__(512, 2) void gemm1_kernel(
        const float* __restrict__ A, const f16* __restrict__ Bt,
        const float* __restrict__ bias, f16* __restrict__ H) {
    constexpr int K = 2048, RN = 256, BK = 32, NT = K / BK;
    __shared__ float4 Asf[2][64 * 8];   // 2 x 8 KB  (A tile f32, swizzled)
    __shared__ f16x8  Bs[2][256 * 4];   // 2 x 16 KB (B tile f16, swizzled)

    const int tid  = threadIdx.x;
    const int lane = tid & 63;
    const int wv   = tid >> 6;              // 0..7
    const int wm   = wv & 1, wn = wv >> 1;  // 2 x 4 wave grid
    const int lr   = lane & 15, q = lane >> 4;
    const int row0 = blockIdx.x << 6;

    f32x4 acc[2][4] = {};

    // Pre-swizzled global sources (swizzle: chunk c of row r -> c ^ (r & mask))
    // A: 64 rows x 8 float4-chunks per tile -> 8 wave-issues, 1 per wave.
    const int La = wv * 64 + lane;
    const int ra = La >> 3, ca = (La & 7) ^ (ra & 7);
    const float* aSrc = A + (size_t)(row0 + ra) * K + ca * 4;
    // B: 256 rows x 4 f16x8-chunks per tile -> 16 wave-issues, 2 per wave.
    const int Lb0 = (wv * 2 + 0) * 64 + lane;
    const int Lb1 = (wv * 2 + 1) * 64 + lane;
    const int rb0 = Lb0 >> 2, cb0 = (Lb0 & 3) ^ (rb0 & 3);
    const int rb1 = Lb1 >> 2, cb1 = (Lb1 & 3) ^ (rb1 & 3);
    const f16* bSrc0 = Bt + (size_t)rb0 * K + cb0 * 8;
    const f16* bSrc1 = Bt + (size_t)rb1 * K + cb1 * 8;

    auto stage = [&](int k0, int b) {   // 3 issues/lane per tile
        async16(aSrc + k0,  (char*)(&Asf[b][0]) + wv * 1024);
        async16(bSrc0 + k0, (char*)(&Bs[b][0]) + (wv * 2 + 0) * 1024);
        async16(bSrc1 + k0, (char*)(&Bs[b][0]) + (wv * 2 + 1) * 1024);
    };

    auto compute = [&](int b) {
        f16x8 af[2], bf[4];
        #pragma unroll
        for (int m = 0; m < 2; m++) {
            int r = wm * 32 + m * 16 + lr;
            float4 v0 = Asf[b][r * 8 + ((2 * q)     ^ (r & 7))];
            float4 v1 = Asf[b][r * 8 + ((2 * q + 1) ^ (r & 7))];
            f16x8 h;
            h[0] = (f16)v0.x; h[1] = (f16)v0.y; h[2] = (f16)v0.z; h[3] = (f16)v0.w;
            h[4] = (f16)v1.x; h[5] = (f16)v1.y; h[6] = (f16)v1.z; h[7] = (f16)v1.w;
            af[m] = h;
        }
        #pragma unroll
        for (int n = 0; n < 4; n++) {
            int r = wn * 64 + n * 16 + lr;
            bf[n] = Bs[b][r * 4 + (q ^ (r & 3))];
        }
        #pragma unroll
        for (int m = 0; m < 2; m++)
            #pragma unroll
            for (int n = 0; n < 4; n++)
                acc[m][n] = __builtin_amdgcn_mfma_f32_16x16x32_f16(
                    af[m], bf[n], acc[m][n], 0, 0, 0);
    };

    stage(0, 0);
    #pragma unroll 2
    for (int t = 0; t < NT - 1; ++t) {
        stage((t + 1) * BK, (t + 1) & 1);   // issue next tile first
        VMCNT(3);                           // wait tile t only; t+1 stays in flight
        SBAR();
        compute(t & 1);
        SBAR();                             // WAR: buf[t&1] rewritten next iter
    }
    VMCNT(0);
    SBAR();
    compute((NT - 1) & 1);

    #pragma unroll
    for (int m = 0; m < 2; m++) {
        int gr0 = row0 + wm * 32 + m * 16 + q * 4;
        #pragma unroll
        for (int n = 0; n < 4; n++) {
            int gc = wn * 64 + n * 16 + lr;
            float bv = bias[gc];
            #pragma unroll
            for (int r = 0; r < 4; r++)
                H[(size_t)(gr0 + r) * RN + gc] = (f16)(acc[m][n][r] + bv);
        }
    }
}

// ---------------------------------------------------------------------------
// GEMM2: y[16384][2048](f32) = H[16384][256](f16) @ W2t[2048][256]^T + b2
// BM=128, BN=256, BK=32, 512 threads (2m x 4n waves, 64x64 wave-tiles).
// Grid = 8 x 128 = 1024 blocks. Same counted-vmcnt double-buffer pipeline.
// Write-bound: 134 MB of Y is the floor.
// ---------------------------------------------------------------------------
__global__ __launch_bounds__(512, 2) void gemm2_kernel(
        const f16* __restrict__ Hs, const f16* __restrict__ Bt,
        const float* __restrict__ bias, float* __restrict__ Y) {
    constexpr int K = 256, N = 2048, BK = 32, NT = K / BK;
    __shared__ f16x8 As[2][128 * 4];   // 2 x 8 KB
    __shared__ f16x8 Bs[2][256 * 4];   // 2 x 16 KB

    const int tid  = threadIdx.x;
    const int lane = tid & 63;
    const int wv   = tid >> 6;
    const int wm   = wv & 1, wn = wv >> 1;
    const int lr   = lane & 15, q = lane >> 4;
    const int row0 = blockIdx.y << 7;
    const int col0 = blockIdx.x << 8;

    f32x4 acc[4][4] = {};

    // A: 128 rows x 4 chunks -> 8 issues, 1/wave.
    const int La = wv * 64 + lane;
    const int ra = La >> 2, ca = (La & 3) ^ (ra & 3);
    const f16* aSrc = Hs + (size_t)(row0 + ra) * K + ca * 8;
    // B: 256 rows x 4 chunks -> 16 issues, 2/wave.
    const int Lb0 = (wv * 2 + 0) * 64 + lane;
    const int Lb1 = (wv * 2 + 1) * 64 + lane;
    const int rb0 = Lb0 >> 2, cb0 = (Lb0 & 3) ^ (rb0 & 3);
    const int rb1 = Lb1 >> 2, cb1 = (Lb1 & 3) ^ (rb1 & 3);
    const f16* bSrc0 = Bt + (size_t)(col0 + rb0) * K + cb0 * 8;
    const f16* bSrc1 = Bt + (size_t)(col0 + rb1) * K + cb1 * 8;

    auto stage = [&](int k0, int b) {   // 3 issues/lane per tile
        async16(aSrc + k0,  (char*)(&As[b][0]) + wv * 1024);
        async16(bSrc0 + k0, (char*)(&Bs[b][0]) + (wv * 2 + 0) * 1024);
        async16(bSrc1 + k0, (char*)(&Bs[b][0]) + (wv * 2 + 1) * 1024);
    };

    auto compute = [&](int b) {
        f16x8 af[4], bf[4];
        #pragma unroll
        for (int m = 0; m < 4; m++) {
            int r = wm * 64 + m * 16 + lr;
            af[m] = As[b][r * 4 + (q ^ (r & 3))];
        }
        #pragma unroll
        for (int n = 0; n < 4; n++) {
            int r = wn * 64 + n * 16 + lr;
            bf[n] = Bs[b][r * 4 + (q ^ (r & 3))];
        }
        #pragma unroll
        for (int m = 0; m < 4; m++)
            #pragma unroll
            for (int n = 0; n < 4; n++)
                acc[m][n] = __builtin_amdgcn_mfma_f32_16x16x32_f16(
                    af[m], bf[n], acc[m][n], 0, 0, 0);
    };

    stage(0, 0);
    for (int t = 0; t < NT - 1; ++t) {
        stage((t + 1) * BK, (t + 1) & 1);
        VMCNT(3);
        SBAR();
        compute(t & 1);
        SBAR();
    }
    VMCNT(0);
    SBAR();
    compute((NT - 1) & 1);

    #pragma unroll
    for (int m = 0; m < 4; m++) {
        int gr0 = row0 + wm * 64 + m * 16 + q * 4;
        #pragma unroll
        for (int n = 0; n < 4; n++) {
            int gc = col0 + wn * 64 + n * 16 + lr;
            float bv = bias[gc];
            #pragma unroll
            for (int r = 0; r < 4; r++)
                Y[(size_t)(gr0 + r) * N + gc] = acc[m][n][r] + bv;
        }
    }
}

// ---------------------------------------------------------------------------
// launch
// ---------------------------------------------------------------------------
extern "C" void kernel_launch(void* const* d_in, const int* in_sizes, int n_in,
                              void* d_out, int out_size, void* d_ws, size_t ws_size,
                              hipStream_t stream) {
    const float* x  = (const float*)d_in[0];   // [8,2048,2048]
    const float* w1 = (const float*)d_in[1];   // [2048,256]
    const float* w2 = (const float*)d_in[2];   // [256,2048]
    const float* b1 = (const float*)d_in[3];   // [256]
    const float* b2 = (const float*)d_in[4];   // [2048]
    const float* s1 = (const float*)d_in[5];   // [1]
    const float* s2 = (const float*)d_in[6];   // [1]
    float* y = (float*)d_out;                  // [8,2048,2048] fp32

    constexpr int NROWS = 8 * 2048;  // 16384
    constexpr int D = 2048, R = 256;

    char* ws = (char*)d_ws;
    f16* W1t = (f16*)ws;                             // [R][D]  fp16, 1 MiB
    f16* W2t = (f16*)(ws + (size_t)R * D * 2);       // [D][R]  fp16, 1 MiB
    f16* H   = (f16*)(ws + (size_t)R * D * 4);       // [NROWS][R] fp16, 8 MiB

    // sparsify + transpose both weights
    hipLaunchKernelGGL(sparsify_t_tiled, dim3(R / 64, D / 64), dim3(256),
                       0, stream, w1, s1, W1t, D, R);
    hipLaunchKernelGGL(sparsify_t_tiled, dim3(D / 64, R / 64), dim3(256),
                       0, stream, w2, s2, W2t, R, D);

    // GEMM1: 256 blocks, one 64-row panel each (full N=256) -> A read once
    hipLaunchKernelGGL(gemm1_kernel, dim3(NROWS / 64), dim3(512),
                       0, stream, x, W1t, b1, H);

    // GEMM2: 8 x 128 = 1024 blocks
    hipLaunchKernelGGL(gemm2_kernel, dim3(D / 256, NROWS / 128), dim3(512),
                       0, stream, H, W2t, b2, y);
}